// Round 3
// baseline (177.446 us; speedup 1.0000x reference)
//
#include <hip/hip_runtime.h>
#include <hip/hip_bf16.h>

// MultiHeadAttention (additive/Bahdanau): B=2, Q=K=256, HIDDEN=1024, 8 heads x 128
// Phase 0: hq' = (query@W_q)*2log2e, hk' = (keys@W_k)*2log2e  (fp32 partials, K-split, to d_ws)
// Phase 1: logits[b,h,q,k] = sum(Va_h) - 2*sum_d Va_d/(2^(hq'+hk')+1) - penalty
// Phase 2: softmax rows in place -> weights; PV -> ctx
//
// tanh(x) = 1 - 2/(e^{2x}+1); with a = 2*log2e*x: e^{2x} = 2^a. Saturates correctly at +-inf.

#define TANH_SCALE 2.88539008177792681472f   // 2*log2(e)
#define LOG2E      1.44269504088896340736f

// ---------------- Phase 0: fp32 GEMM, partial C = scale * A[512,Kslice] @ W[Kslice,1024] ----------------
// grid.z: bit0 = {query,keys}, bits>=1 = K-split index. parts layout: [ks*2+zq][512*1024]
// Double-buffered LDS: one barrier per K-step.
__global__ __launch_bounds__(256) void gemm2_f32(
    const float* __restrict__ query, const float* __restrict__ keys,
    const float* __restrict__ Wq, const float* __restrict__ Wk,
    float* __restrict__ parts, int ksplit)
{
  const int z = blockIdx.z;
  const int zq = z & 1, ks = z >> 1;
  const float* A = zq ? keys : query;
  const float* W = zq ? Wk : Wq;
  float* out = parts + (size_t)(ks * 2 + zq) * 524288;
  const int klen = 1024 / ksplit;
  const int kbeg = ks * klen, kend = kbeg + klen;

  __shared__ __align__(16) float As[2][16 * 68];  // [k][m], stride 68 (16B-aligned rows)
  __shared__ __align__(16) float Ws[2][16 * 64];  // [k][n]

  const int tid = threadIdx.x;
  const int tx = tid & 15, ty = tid >> 4;
  const int m0 = blockIdx.y * 64, n0 = blockIdx.x * 64;

  const int ak = tid & 15, am = tid >> 4;   // A tile 64m x 16k
  const int wn = tid & 63, wk = tid >> 6;   // W tile 16k x 64n

  float ar[4], wr[4];
#pragma unroll
  for (int i = 0; i < 4; ++i) ar[i] = A[(m0 + am + i * 16) * 1024 + kbeg + ak];
#pragma unroll
  for (int i = 0; i < 4; ++i) wr[i] = W[(kbeg + wk + i * 4) * 1024 + n0 + wn];

#pragma unroll
  for (int i = 0; i < 4; ++i) As[0][ak * 68 + am + i * 16] = ar[i];
#pragma unroll
  for (int i = 0; i < 4; ++i) Ws[0][(wk + i * 4) * 64 + wn] = wr[i];
  __syncthreads();

  float acc[4][4] = {};
  int cur = 0;

  for (int kk = kbeg; kk < kend; kk += 16) {
    const bool more = (kk + 16) < kend;
    if (more) {  // prefetch next tile into registers (in flight during compute)
#pragma unroll
      for (int i = 0; i < 4; ++i) ar[i] = A[(m0 + am + i * 16) * 1024 + kk + 16 + ak];
#pragma unroll
      for (int i = 0; i < 4; ++i) wr[i] = W[(kk + 16 + wk + i * 4) * 1024 + n0 + wn];
    }

#pragma unroll
    for (int k = 0; k < 16; ++k) {
      float4 af = *(const float4*)&As[cur][k * 68 + ty * 4];
      float4 wf = *(const float4*)&Ws[cur][k * 64 + tx * 4];
      float a[4] = {af.x, af.y, af.z, af.w};
      float w[4] = {wf.x, wf.y, wf.z, wf.w};
#pragma unroll
      for (int i = 0; i < 4; ++i)
#pragma unroll
        for (int j = 0; j < 4; ++j) acc[i][j] += a[i] * w[j];
    }

    if (more) {  // write next tile to the other buffer; single barrier per step
#pragma unroll
      for (int i = 0; i < 4; ++i) As[cur ^ 1][ak * 68 + am + i * 16] = ar[i];
#pragma unroll
      for (int i = 0; i < 4; ++i) Ws[cur ^ 1][(wk + i * 4) * 64 + wn] = wr[i];
      __syncthreads();
      cur ^= 1;
    }
  }

#pragma unroll
  for (int i = 0; i < 4; ++i) {
    float4 o;
    o.x = acc[i][0] * TANH_SCALE; o.y = acc[i][1] * TANH_SCALE;
    o.z = acc[i][2] * TANH_SCALE; o.w = acc[i][3] * TANH_SCALE;
    *(float4*)&out[(m0 + ty * 4 + i) * 1024 + n0 + tx * 4] = o;
  }
}

// ---------------- Phase 1: logits ----------------
// grid: x = k-tile (8, TK=32), y = q-tile (32, TQ=8), z = b + 2*headgroup (2 heads per block)
// LDS layout: row stride 132 words; float4 quad at logical (r, d4) stored at quad index (d4 ^ (r>>3))
// -> ds_read_b128 across lanes kl=0..31 is bank-conflict-free.
__global__ __launch_bounds__(256) void logits_kernel(
    const float* __restrict__ parts,
    const float* __restrict__ Va, const int* __restrict__ mask,
    float* __restrict__ logits /* [B,8,Q,K] */, int nparts)
{
  __shared__ __align__(16) float hk_s[32 * 132];
  __shared__ __align__(16) float hq_s[8 * 132];

  const int tid = threadIdx.x;
  const int b  = blockIdx.z & 1;
  const int h0 = (blockIdx.z >> 1) * 2;       // first of 2 heads
  const int q0 = blockIdx.y * 8, k0 = blockIdx.x * 32;

  const int kl = tid & 31;   // key within tile
  const int qs = tid >> 5;   // query within tile (0..7)
  const int kswz = kl >> 3;  // b128 read swizzle
  const float pen = 99.0f * (1.0f - (float)mask[b * 256 + k0 + kl]);

  float pf_hq[4], pf_hk[16];
  // prefetch head h0
#pragma unroll
  for (int i = 0; i < 4; ++i) {
    int idx = tid + i * 256; int r = idx >> 7, d = idx & 127;
    size_t o = (size_t)(b * 256 + q0 + r) * 1024 + h0 * 128 + d;
    float v = parts[o];
    if (nparts > 1) v += parts[o + 2 * 524288];
    if (nparts > 2) v += parts[o + 4 * 524288] + parts[o + 6 * 524288];
    pf_hq[i] = v;
  }
#pragma unroll
  for (int i = 0; i < 16; ++i) {
    int idx = tid + i * 256; int r = idx >> 7, d = idx & 127;
    size_t o = (size_t)(b * 256 + k0 + r) * 1024 + h0 * 128 + d + 524288;
    float v = parts[o];
    if (nparts > 1) v += parts[o + 2 * 524288];
    if (nparts > 2) v += parts[o + 4 * 524288] + parts[o + 6 * 524288];
    pf_hk[i] = v;
  }

  for (int c = 0; c < 2; ++c) {   // one head (128 d) per chunk
    const int head = h0 + c;
    const float* vaH = Va + head * 128;
    __syncthreads();
#pragma unroll
    for (int i = 0; i < 4; ++i) {
      int idx = tid + i * 256; int r = idx >> 7, d = idx & 127;
      hq_s[r * 132 + ((((d >> 2) ^ (r >> 3)) & 31) << 2) + (d & 3)] = pf_hq[i];
    }
#pragma unroll
    for (int i = 0; i < 16; ++i) {
      int idx = tid + i * 256; int r = idx >> 7, d = idx & 127;
      hk_s[r * 132 + ((((d >> 2) ^ (r >> 3)) & 31) << 2) + (d & 3)] = pf_hk[i];
    }
    __syncthreads();

    if (c < 1) {  // prefetch next head under compute
      int c1 = (head + 1) * 128;
#pragma unroll
      for (int i = 0; i < 4; ++i) {
        int idx = tid + i * 256; int r = idx >> 7, d = idx & 127;
        size_t o = (size_t)(b * 256 + q0 + r) * 1024 + c1 + d;
        float v = parts[o];
        if (nparts > 1) v += parts[o + 2 * 524288];
        if (nparts > 2) v += parts[o + 4 * 524288] + parts[o + 6 * 524288];
        pf_hq[i] = v;
      }
#pragma unroll
      for (int i = 0; i < 16; ++i) {
        int idx = tid + i * 256; int r = idx >> 7, d = idx & 127;
        size_t o = (size_t)(b * 256 + k0 + r) * 1024 + c1 + d + 524288;
        float v = parts[o];
        if (nparts > 1) v += parts[o + 2 * 524288];
        if (nparts > 2) v += parts[o + 4 * 524288] + parts[o + 6 * 524288];
        pf_hk[i] = v;
      }
    }

    // ssum = sum(Va over this head): 2 loads + butterfly
    float ssum = vaH[tid & 63] + vaH[(tid & 63) + 64];
#pragma unroll
    for (int off = 32; off; off >>= 1) ssum += __shfl_xor(ssum, off, 64);

    const float* hqrow = hq_s + qs * 132;   // qs<8 -> qs>>3==0, no swizzle on read
    const float* hkrow = hk_s + kl * 132;
    float s0 = 0.f, s1 = 0.f, s2 = 0.f, s3 = 0.f;
#pragma unroll 8
    for (int d4 = 0; d4 < 32; ++d4) {
      float4 hqv = *(const float4*)(hqrow + (d4 << 2));
      float4 hkv = *(const float4*)(hkrow + (((d4 ^ kswz) & 31) << 2));
      float e0 = __builtin_amdgcn_exp2f(hqv.x + hkv.x);
      float e1 = __builtin_amdgcn_exp2f(hqv.y + hkv.y);
      float e2 = __builtin_amdgcn_exp2f(hqv.z + hkv.z);
      float e3 = __builtin_amdgcn_exp2f(hqv.w + hkv.w);
      s0 += vaH[d4 * 4 + 0] * __builtin_amdgcn_rcpf(e0 + 1.0f);
      s1 += vaH[d4 * 4 + 1] * __builtin_amdgcn_rcpf(e1 + 1.0f);
      s2 += vaH[d4 * 4 + 2] * __builtin_amdgcn_rcpf(e2 + 1.0f);
      s3 += vaH[d4 * 4 + 3] * __builtin_amdgcn_rcpf(e3 + 1.0f);
    }
    float logit = ssum - 2.0f * ((s0 + s1) + (s2 + s3)) - pen;
    logits[((size_t)(b * 8 + head) * 256 + q0 + qs) * 256 + k0 + kl] = logit;
  }
}

// ---------------- Phase 2: softmax (in place) + PV ----------------
// grid: x = q-tile (32, TQ=8), y = h, z = b
__global__ __launch_bounds__(256) void softmax_pv(
    const float* __restrict__ values,
    float* __restrict__ weights,   // in: logits (penalty baked), out: softmax weights
    float* __restrict__ ctx)       // [B,Q,1024]
{
  __shared__ __align__(16) float w_lds[8 * 256];
  const int tid = threadIdx.x;
  const int b = blockIdx.z, h = blockIdx.y, q0 = blockIdx.x * 8;
  const int wave = tid >> 6, lane = tid & 63;

#pragma unroll
  for (int r = 0; r < 2; ++r) {
    const int row = wave * 2 + r;     // 0..7
    float* lp = &weights[((size_t)(b * 8 + h) * 256 + q0 + row) * 256];
    float4 L = *(const float4*)&lp[lane * 4];
    float m = fmaxf(fmaxf(L.x, L.y), fmaxf(L.z, L.w));
#pragma unroll
    for (int off = 32; off; off >>= 1) m = fmaxf(m, __shfl_xor(m, off, 64));
    float4 P;
    P.x = __builtin_amdgcn_exp2f((L.x - m) * LOG2E);
    P.y = __builtin_amdgcn_exp2f((L.y - m) * LOG2E);
    P.z = __builtin_amdgcn_exp2f((L.z - m) * LOG2E);
    P.w = __builtin_amdgcn_exp2f((L.w - m) * LOG2E);
    float s = (P.x + P.y) + (P.z + P.w);
#pragma unroll
    for (int off = 32; off; off >>= 1) s += __shfl_xor(s, off, 64);
    float inv = 1.0f / s;   // accurate division
    P.x *= inv; P.y *= inv; P.z *= inv; P.w *= inv;
    *(float4*)&w_lds[row * 256 + lane * 4] = P;
    *(float4*)&lp[lane * 4] = P;
  }
  __syncthreads();

  // PV: thread -> (q = tid>>5, d4 = (tid&31)*4); loop k, coalesced float4 V loads
  const int q = tid >> 5, dq = tid & 31;
  const float* vb = values + (size_t)(b * 256) * 1024 + h * 128 + dq * 4;
  const float* wrow = w_lds + q * 256;
  float4 accE = make_float4(0, 0, 0, 0), accO = make_float4(0, 0, 0, 0);
#pragma unroll 4
  for (int k = 0; k < 256; k += 2) {
    float4 v0 = *(const float4*)&vb[k * 1024];
    float4 v1 = *(const float4*)&vb[(k + 1) * 1024];
    float w0 = wrow[k], w1 = wrow[k + 1];
    accE.x += w0 * v0.x; accE.y += w0 * v0.y; accE.z += w0 * v0.z; accE.w += w0 * v0.w;
    accO.x += w1 * v1.x; accO.y += w1 * v1.y; accO.z += w1 * v1.z; accO.w += w1 * v1.w;
  }
  float4 o;
  o.x = accE.x + accO.x; o.y = accE.y + accO.y; o.z = accE.z + accO.z; o.w = accE.w + accO.w;
  *(float4*)&ctx[(size_t)(b * 256 + q0 + q) * 1024 + h * 128 + dq * 4] = o;
}

extern "C" void kernel_launch(void* const* d_in, const int* in_sizes, int n_in,
                              void* d_out, int out_size, void* d_ws, size_t ws_size,
                              hipStream_t stream) {
  const float* query  = (const float*)d_in[0];
  const float* keys   = (const float*)d_in[1];
  const float* values = (const float*)d_in[2];
  const int*   mask   = (const int*)d_in[3];
  const float* Wq     = (const float*)d_in[4];
  const float* Wk     = (const float*)d_in[5];
  const float* Va     = (const float*)d_in[6];

  float* ctx     = (float*)d_out;            // [2,256,1024] = 524288 floats
  float* weights = ctx + 524288;             // [2,8,256,256] = 1048576 floats
  float* parts   = (float*)d_ws;             // ksplit*2 x 524288 floats (K-split partials)

  const int ksplit = (ws_size >= (size_t)16 * 1024 * 1024) ? 4
                   : (ws_size >= (size_t)8 * 1024 * 1024) ? 2 : 1;

  gemm2_f32<<<dim3(16, 8, 2 * ksplit), 256, 0, stream>>>(query, keys, Wq, Wk, parts, ksplit);
  logits_kernel<<<dim3(8, 32, 8), 256, 0, stream>>>(parts, Va, mask, weights, ksplit);
  softmax_pv<<<dim3(32, 8, 2), 256, 0, stream>>>(values, weights, ctx);
}

// Round 4
// 91.860 us; speedup vs baseline: 1.9317x; 1.9317x over previous
//
#include <hip/hip_runtime.h>
#include <hip/hip_bf16.h>

// MultiHeadAttention (additive/Bahdanau): B=2, Q=K=256, HIDDEN=1024, 8 heads x 128
// Phase 0: hq' = (query@W_q)*2log2e, hk' = (keys@W_k)*2log2e  (fp32 K-split partials, to d_ws)
// Phase 0.5: reduce partials -> hq_f[512][1024]; reduce+transpose -> hkT[1024][512]
// Phase 1: logits[b,h,q,k] = sum(Va_h) - 2*sum_d Va_d/(2^(hq'+hk')+1) - penalty
//          lanes->keys (coalesced hkT dwordx4), hq/Va wave-uniform (s_load), accs in VGPRs. No LDS.
// Phase 2: softmax rows in place -> weights; PV -> ctx
//
// tanh(x) = 1 - 2/(e^{2x}+1); a = 2log2e*x -> e^{2x} = 2^a. exp2 overflow->inf->rcp->0: saturates right.

#define TANH_SCALE 2.88539008177792681472f   // 2*log2(e)
#define LOG2E      1.44269504088896340736f

// ---------------- Phase 0: fp32 GEMM (R1-proven), partial C = scale*A[512,Kslice]@W[Kslice,1024] ----
// grid.z: bit0 = {query,keys}, bit1 = K-split index (ksplit=2). parts: [ks*2+zq][512*1024]
__global__ __launch_bounds__(256) void gemm2_f32(
    const float* __restrict__ query, const float* __restrict__ keys,
    const float* __restrict__ Wq, const float* __restrict__ Wk,
    float* __restrict__ parts)
{
  const int z = blockIdx.z;
  const int zq = z & 1, ks = z >> 1;
  const float* A = zq ? keys : query;
  const float* W = zq ? Wk : Wq;
  float* out = parts + (size_t)(ks * 2 + zq) * 524288;
  const int kbeg = ks * 512, kend = kbeg + 512;

  __shared__ __align__(16) float As[16 * 68];
  __shared__ __align__(16) float Ws[16 * 64];

  const int tid = threadIdx.x;
  const int tx = tid & 15, ty = tid >> 4;
  const int m0 = blockIdx.y * 64, n0 = blockIdx.x * 64;

  const int ak = tid & 15, am = tid >> 4;
  const int wn = tid & 63, wk = tid >> 6;

  float ar[4], wr[4];
#pragma unroll
  for (int i = 0; i < 4; ++i) ar[i] = A[(m0 + am + i * 16) * 1024 + kbeg + ak];
#pragma unroll
  for (int i = 0; i < 4; ++i) wr[i] = W[(kbeg + wk + i * 4) * 1024 + n0 + wn];

  float acc[4][4] = {};

  for (int kk = kbeg; kk < kend; kk += 16) {
    __syncthreads();
#pragma unroll
    for (int i = 0; i < 4; ++i) As[ak * 68 + am + i * 16] = ar[i];
#pragma unroll
    for (int i = 0; i < 4; ++i) Ws[(wk + i * 4) * 64 + wn] = wr[i];
    __syncthreads();

    if (kk + 16 < kend) {
#pragma unroll
      for (int i = 0; i < 4; ++i) ar[i] = A[(m0 + am + i * 16) * 1024 + kk + 16 + ak];
#pragma unroll
      for (int i = 0; i < 4; ++i) wr[i] = W[(kk + 16 + wk + i * 4) * 1024 + n0 + wn];
    }

#pragma unroll
    for (int k = 0; k < 16; ++k) {
      float4 af = *(const float4*)&As[k * 68 + ty * 4];
      float4 wf = *(const float4*)&Ws[k * 64 + tx * 4];
      float a[4] = {af.x, af.y, af.z, af.w};
      float w[4] = {wf.x, wf.y, wf.z, wf.w};
#pragma unroll
      for (int i = 0; i < 4; ++i)
#pragma unroll
        for (int j = 0; j < 4; ++j) acc[i][j] += a[i] * w[j];
    }
  }

#pragma unroll
  for (int i = 0; i < 4; ++i) {
    float4 o;
    o.x = acc[i][0] * TANH_SCALE; o.y = acc[i][1] * TANH_SCALE;
    o.z = acc[i][2] * TANH_SCALE; o.w = acc[i][3] * TANH_SCALE;
    *(float4*)&out[(m0 + ty * 4 + i) * 1024 + n0 + tx * 4] = o;
  }
}

// ---------------- Phase 0.5: reduce partials; transpose hk ----------------
// blocks 0..127: hk 64x64 transpose tiles (m0=(bid&7)*64, d0=(bid>>3)*64)
// blocks 128..159: hq elementwise reduce
__global__ __launch_bounds__(256) void reduce_transpose(
    const float* __restrict__ parts, float* __restrict__ hq_f, float* __restrict__ hkT)
{
  const int bid = blockIdx.x, tid = threadIdx.x;
  if (bid < 128) {
    __shared__ float tile[64][65];
    const int m0 = (bid & 7) * 64, d0 = (bid >> 3) * 64;
    const float* p0 = parts + 524288;    // ks0 hk
    const float* p1 = parts + 1572864;   // ks1 hk
    const int r = tid >> 4, c = (tid & 15) * 4;
#pragma unroll
    for (int i = 0; i < 4; ++i) {
      const int rr = r + i * 16;
      size_t off = (size_t)(m0 + rr) * 1024 + d0 + c;
      float4 a = *(const float4*)(p0 + off);
      float4 bq = *(const float4*)(p1 + off);
      tile[rr][c + 0] = a.x + bq.x;
      tile[rr][c + 1] = a.y + bq.y;
      tile[rr][c + 2] = a.z + bq.z;
      tile[rr][c + 3] = a.w + bq.w;
    }
    __syncthreads();
#pragma unroll
    for (int i = 0; i < 4; ++i) {
      const int rr = r + i * 16;
      float4 o;
      o.x = tile[c + 0][rr]; o.y = tile[c + 1][rr];
      o.z = tile[c + 2][rr]; o.w = tile[c + 3][rr];
      *(float4*)(hkT + (size_t)(d0 + rr) * 512 + m0 + c) = o;
    }
  } else {
    const int cb = bid - 128;
    const float* p0 = parts;              // ks0 hq
    const float* p1 = parts + 1048576;    // ks1 hq
    const size_t base = (size_t)cb * 16384;
#pragma unroll
    for (int i = 0; i < 16; ++i) {
      size_t o = base + (size_t)(tid + i * 256) * 4;
      float4 a = *(const float4*)(p0 + o);
      float4 bq = *(const float4*)(p1 + o);
      a.x += bq.x; a.y += bq.y; a.z += bq.z; a.w += bq.w;
      *(float4*)(hq_f + o) = a;
    }
  }
}

// ---------------- Phase 1: logits, LDS-free ----------------
// 512 blocks x 4 waves. Wave: (b,h) = bid>>5, qb = (bid&31)*4 + wave, q0 = 2*qb.
// Lane l covers k = 4l..4l+3 (all 256 k). Loop d in groups of 4.
#define COMP(vk, hq0v, hq1v, vad)                                     \
  {                                                                   \
    float e0 = __builtin_amdgcn_exp2f(hq0v + vk.x);                   \
    float e1 = __builtin_amdgcn_exp2f(hq0v + vk.y);                   \
    float e2 = __builtin_amdgcn_exp2f(hq0v + vk.z);                   \
    float e3 = __builtin_amdgcn_exp2f(hq0v + vk.w);                   \
    acc00 += vad * __builtin_amdgcn_rcpf(e0 + 1.0f);                  \
    acc01 += vad * __builtin_amdgcn_rcpf(e1 + 1.0f);                  \
    acc02 += vad * __builtin_amdgcn_rcpf(e2 + 1.0f);                  \
    acc03 += vad * __builtin_amdgcn_rcpf(e3 + 1.0f);                  \
    float f0 = __builtin_amdgcn_exp2f(hq1v + vk.x);                   \
    float f1 = __builtin_amdgcn_exp2f(hq1v + vk.y);                   \
    float f2 = __builtin_amdgcn_exp2f(hq1v + vk.z);                   \
    float f3 = __builtin_amdgcn_exp2f(hq1v + vk.w);                   \
    acc10 += vad * __builtin_amdgcn_rcpf(f0 + 1.0f);                  \
    acc11 += vad * __builtin_amdgcn_rcpf(f1 + 1.0f);                  \
    acc12 += vad * __builtin_amdgcn_rcpf(f2 + 1.0f);                  \
    acc13 += vad * __builtin_amdgcn_rcpf(f3 + 1.0f);                  \
  }

__global__ __launch_bounds__(256) void logits_v3(
    const float* __restrict__ hq_f, const float* __restrict__ hkT,
    const float* __restrict__ Va, const int* __restrict__ mask,
    float* __restrict__ logits)
{
  const int tid = threadIdx.x;
  const int lane = tid & 63;
  const int w = __builtin_amdgcn_readfirstlane(tid >> 6);
  const int bid = blockIdx.x;
  const int hb = bid >> 5;           // 0..15
  const int b = hb & 1, h = hb >> 1;
  const int qb = (bid & 31) * 4 + w; // 0..127
  const int q0 = qb * 2;

  int4 mk = *(const int4*)(mask + b * 256 + 4 * lane);
  const float pen0 = 99.0f * (1.0f - (float)mk.x);
  const float pen1 = 99.0f * (1.0f - (float)mk.y);
  const float pen2 = 99.0f * (1.0f - (float)mk.z);
  const float pen3 = 99.0f * (1.0f - (float)mk.w);

  // ssum = sum(Va over this head)
  float ssum = Va[h * 128 + lane] + Va[h * 128 + 64 + lane];
#pragma unroll
  for (int off = 32; off; off >>= 1) ssum += __shfl_xor(ssum, off, 64);

  const float* hkbase = hkT + (size_t)(h * 128) * 512 + b * 256 + 4 * lane;
  const float* hqr0 = hq_f + (size_t)(b * 256 + q0) * 1024 + h * 128;  // wave-uniform
  const float* hqr1 = hqr0 + 1024;
  const float* vap = Va + h * 128;

  float acc00 = 0.f, acc01 = 0.f, acc02 = 0.f, acc03 = 0.f;
  float acc10 = 0.f, acc11 = 0.f, acc12 = 0.f, acc13 = 0.f;

  float4 vk0 = *(const float4*)(hkbase + 0 * 512);
  float4 vk1 = *(const float4*)(hkbase + 1 * 512);
  float4 vk2 = *(const float4*)(hkbase + 2 * 512);
  float4 vk3 = *(const float4*)(hkbase + 3 * 512);
  float4 hqA = *(const float4*)(hqr0);
  float4 hqB = *(const float4*)(hqr1);
  float4 va4 = *(const float4*)(vap);

  for (int g = 0; g < 32; ++g) {
    float4 nvk0, nvk1, nvk2, nvk3, nhqA, nhqB, nva4;
    if (g < 31) {  // prefetch next d-group (uniform branch)
      const float* hb2 = hkbase + (size_t)(4 * g + 4) * 512;
      nvk0 = *(const float4*)(hb2 + 0 * 512);
      nvk1 = *(const float4*)(hb2 + 1 * 512);
      nvk2 = *(const float4*)(hb2 + 2 * 512);
      nvk3 = *(const float4*)(hb2 + 3 * 512);
      nhqA = *(const float4*)(hqr0 + 4 * g + 4);
      nhqB = *(const float4*)(hqr1 + 4 * g + 4);
      nva4 = *(const float4*)(vap + 4 * g + 4);
    }
    COMP(vk0, hqA.x, hqB.x, va4.x);
    COMP(vk1, hqA.y, hqB.y, va4.y);
    COMP(vk2, hqA.z, hqB.z, va4.z);
    COMP(vk3, hqA.w, hqB.w, va4.w);
    if (g < 31) {
      vk0 = nvk0; vk1 = nvk1; vk2 = nvk2; vk3 = nvk3;
      hqA = nhqA; hqB = nhqB; va4 = nva4;
    }
  }

  float* lp = logits + ((size_t)((b * 8 + h) * 256) + q0) * 256 + 4 * lane;
  float4 o0, o1;
  o0.x = ssum - 2.0f * acc00 - pen0;
  o0.y = ssum - 2.0f * acc01 - pen1;
  o0.z = ssum - 2.0f * acc02 - pen2;
  o0.w = ssum - 2.0f * acc03 - pen3;
  o1.x = ssum - 2.0f * acc10 - pen0;
  o1.y = ssum - 2.0f * acc11 - pen1;
  o1.z = ssum - 2.0f * acc12 - pen2;
  o1.w = ssum - 2.0f * acc13 - pen3;
  *(float4*)(lp) = o0;
  *(float4*)(lp + 256) = o1;
}

// ---------------- Phase 2: softmax (in place) + PV ----------------
__global__ __launch_bounds__(256) void softmax_pv(
    const float* __restrict__ values,
    float* __restrict__ weights,
    float* __restrict__ ctx)
{
  __shared__ __align__(16) float w_lds[8 * 256];
  const int tid = threadIdx.x;
  const int b = blockIdx.z, h = blockIdx.y, q0 = blockIdx.x * 8;
  const int wave = tid >> 6, lane = tid & 63;

#pragma unroll
  for (int r = 0; r < 2; ++r) {
    const int row = wave * 2 + r;
    float* lp = &weights[((size_t)(b * 8 + h) * 256 + q0 + row) * 256];
    float4 L = *(const float4*)&lp[lane * 4];
    float m = fmaxf(fmaxf(L.x, L.y), fmaxf(L.z, L.w));
#pragma unroll
    for (int off = 32; off; off >>= 1) m = fmaxf(m, __shfl_xor(m, off, 64));
    float4 P;
    P.x = __builtin_amdgcn_exp2f((L.x - m) * LOG2E);
    P.y = __builtin_amdgcn_exp2f((L.y - m) * LOG2E);
    P.z = __builtin_amdgcn_exp2f((L.z - m) * LOG2E);
    P.w = __builtin_amdgcn_exp2f((L.w - m) * LOG2E);
    float s = (P.x + P.y) + (P.z + P.w);
#pragma unroll
    for (int off = 32; off; off >>= 1) s += __shfl_xor(s, off, 64);
    float inv = 1.0f / s;
    P.x *= inv; P.y *= inv; P.z *= inv; P.w *= inv;
    *(float4*)&w_lds[row * 256 + lane * 4] = P;
    *(float4*)&lp[lane * 4] = P;
  }
  __syncthreads();

  const int q = tid >> 5, dq = tid & 31;
  const float* vb = values + (size_t)(b * 256) * 1024 + h * 128 + dq * 4;
  const float* wrow = w_lds + q * 256;
  float4 accE = make_float4(0, 0, 0, 0), accO = make_float4(0, 0, 0, 0);
#pragma unroll 4
  for (int k = 0; k < 256; k += 2) {
    float4 v0 = *(const float4*)&vb[k * 1024];
    float4 v1 = *(const float4*)&vb[(k + 1) * 1024];
    float w0 = wrow[k], w1 = wrow[k + 1];
    accE.x += w0 * v0.x; accE.y += w0 * v0.y; accE.z += w0 * v0.z; accE.w += w0 * v0.w;
    accO.x += w1 * v1.x; accO.y += w1 * v1.y; accO.z += w1 * v1.z; accO.w += w1 * v1.w;
  }
  float4 o;
  o.x = accE.x + accO.x; o.y = accE.y + accO.y; o.z = accE.z + accO.z; o.w = accE.w + accO.w;
  *(float4*)&ctx[(size_t)(b * 256 + q0 + q) * 1024 + h * 128 + dq * 4] = o;
}

extern "C" void kernel_launch(void* const* d_in, const int* in_sizes, int n_in,
                              void* d_out, int out_size, void* d_ws, size_t ws_size,
                              hipStream_t stream) {
  const float* query  = (const float*)d_in[0];
  const float* keys   = (const float*)d_in[1];
  const float* values = (const float*)d_in[2];
  const int*   mask   = (const int*)d_in[3];
  const float* Wq     = (const float*)d_in[4];
  const float* Wk     = (const float*)d_in[5];
  const float* Va     = (const float*)d_in[6];

  float* ctx     = (float*)d_out;            // [2,256,1024]
  float* weights = ctx + 524288;             // [2,8,256,256]
  float* parts   = (float*)d_ws;             // 4 x 524288 (ks x {q,k} partials) = 8 MB
  float* hq_f    = parts + 2097152;          // [512][1024] = 2 MB
  float* hkT     = parts + 2621440;          // [1024][512] = 2 MB  (total 12 MB <= ws)

  gemm2_f32<<<dim3(16, 8, 4), 256, 0, stream>>>(query, keys, Wq, Wk, parts);
  reduce_transpose<<<dim3(160), 256, 0, stream>>>(parts, hq_f, hkT);
  logits_v3<<<dim3(512), 256, 0, stream>>>(hq_f, hkT, Va, mask, weights);
  softmax_pv<<<dim3(32, 8, 2), 256, 0, stream>>>(values, weights, ctx);
}

// Round 5
// 77.563 us; speedup vs baseline: 2.2878x; 1.1843x over previous
//
#include <hip/hip_runtime.h>
#include <hip/hip_bf16.h>

// MultiHeadAttention (additive/Bahdanau): B=2, Q=K=256, HIDDEN=1024, 8 heads x 128
// Phase 0a: split query/keys into bf16 hi/lo (Markidis 3-term split)
// Phase 0b: split W^T * 2log2e into bf16 hi/lo (LDS transpose)
// Phase 1:  MFMA bf16 GEMMs (hh + hl + lh terms, fp32 accum):
//             z=0: hq_f[m][n]  = qs[m][h] . WqT[n][h]
//             z=1: hkT[n][m]   = WkT[n][h] . ks[m][h]   (transposed output for free)
// Phase 2:  logits[b,h,q,k] = sum(Va_h) - 2*sum_d Va_d/(2^(hq'+hk')+1) - penalty  (LDS-free)
// Phase 3:  softmax rows in place -> weights; PV -> ctx
// NOTE: requires ws_size >= 16 MB (verified present in earlier rounds).

#define TANH_SCALE 2.88539008177792681472f   // 2*log2(e)
#define LOG2E      1.44269504088896340736f

typedef __attribute__((ext_vector_type(8))) short bf16x8_t;   // 8 bf16 = 4 VGPRs
typedef __attribute__((ext_vector_type(4))) float f32x4_t;

__device__ inline ushort bf16_rne(float f) {
  unsigned u = __float_as_uint(f);
  u += 0x7FFFu + ((u >> 16) & 1u);
  return (ushort)(u >> 16);
}
__device__ inline float bf16_to_f(ushort h) { return __uint_as_float((unsigned)h << 16); }
__device__ inline void split1(float v, ushort& hi, ushort& lo) {
  hi = bf16_rne(v);
  lo = bf16_rne(v - bf16_to_f(hi));
}

// ---------------- Phase 0a: elementwise hi/lo split of query & keys ----------------
// grid (512, 2) x 256 thr, 4 elems/thread
__global__ __launch_bounds__(256) void split_A(
    const float* __restrict__ query, const float* __restrict__ keys,
    ushort* __restrict__ qhi, ushort* __restrict__ qlo,
    ushort* __restrict__ khi, ushort* __restrict__ klo)
{
  const int z = blockIdx.y;
  const float* in = z ? keys : query;
  ushort* hi = z ? khi : qhi;
  ushort* lo = z ? klo : qlo;
  const size_t i = ((size_t)blockIdx.x * 256 + threadIdx.x) * 4;
  float4 v = *(const float4*)(in + i);
  ushort h0, h1, h2, h3, l0, l1, l2, l3;
  split1(v.x, h0, l0); split1(v.y, h1, l1);
  split1(v.z, h2, l2); split1(v.w, h3, l3);
  *(ushort4*)(hi + i) = make_ushort4(h0, h1, h2, h3);
  *(ushort4*)(lo + i) = make_ushort4(l0, l1, l2, l3);
}

// ---------------- Phase 0b: W^T * scale, hi/lo split ----------------
// grid (16 n-tiles, 16 h-tiles, 2), 256 thr. WT[n][h] = W[h][n]*TANH_SCALE.
__global__ __launch_bounds__(256) void split_WT(
    const float* __restrict__ Wq, const float* __restrict__ Wk,
    ushort* __restrict__ wqthi, ushort* __restrict__ wqtlo,
    ushort* __restrict__ wkthi, ushort* __restrict__ wktlo)
{
  const int z = blockIdx.z;
  const float* W = z ? Wk : Wq;
  ushort* thi = z ? wkthi : wqthi;
  ushort* tlo = z ? wktlo : wqtlo;
  __shared__ float t[64][65];
  const int tid = threadIdx.x;
  const int n0 = blockIdx.x * 64, h0 = blockIdx.y * 64;
  const int r = tid >> 4, c = (tid & 15) * 4;
#pragma unroll
  for (int i = 0; i < 4; ++i) {
    const int rr = r + i * 16;
    float4 wv = *(const float4*)(W + (size_t)(h0 + rr) * 1024 + n0 + c);
    t[rr][c + 0] = wv.x; t[rr][c + 1] = wv.y;
    t[rr][c + 2] = wv.z; t[rr][c + 3] = wv.w;
  }
  __syncthreads();
#pragma unroll
  for (int i = 0; i < 4; ++i) {
    const int rr = r + i * 16;   // local n row of output
    ushort h0v, h1v, h2v, h3v, l0v, l1v, l2v, l3v;
    split1(t[c + 0][rr] * TANH_SCALE, h0v, l0v);
    split1(t[c + 1][rr] * TANH_SCALE, h1v, l1v);
    split1(t[c + 2][rr] * TANH_SCALE, h2v, l2v);
    split1(t[c + 3][rr] * TANH_SCALE, h3v, l3v);
    *(ushort4*)(thi + (size_t)(n0 + rr) * 1024 + h0 + c) = make_ushort4(h0v, h1v, h2v, h3v);
    *(ushort4*)(tlo + (size_t)(n0 + rr) * 1024 + h0 + c) = make_ushort4(l0v, l1v, l2v, l3v);
  }
}

// ---------------- Phase 1: MFMA GEMM, 3-term bf16 split ----------------
// grid (128, 2). Block: 64x64 C-tile, 4 waves of 32x32, K-step 32, K=1024.
// All operand sources have row-stride 1024 over the contraction dim.
// A-frag: row = lane&15 (+16*fm), k = (lane>>4)*8 + e.  B-frag symmetric (col rows).
// C/D: col = lane&15, row = (lane>>4)*4 + j.
__global__ __launch_bounds__(256) void gemm_mfma(
    const ushort* __restrict__ qhi, const ushort* __restrict__ qlo,
    const ushort* __restrict__ khi, const ushort* __restrict__ klo,
    const ushort* __restrict__ wqthi, const ushort* __restrict__ wqtlo,
    const ushort* __restrict__ wkthi, const ushort* __restrict__ wktlo,
    float* __restrict__ hq_f, float* __restrict__ hkT)
{
  const int z = blockIdx.y;
  const int bid = blockIdx.x;
  int m0, n0, ldc;
  const ushort *Ah_g, *Al_g, *Bh_g, *Bl_g;
  float* C;
  if (z == 0) {             // hq_f[512][1024]: A = query-split (M=512), B = WqT (N=1024)
    m0 = (bid >> 4) * 64; n0 = (bid & 15) * 64; ldc = 1024;
    Ah_g = qhi; Al_g = qlo; Bh_g = wqthi; Bl_g = wqtlo; C = hq_f;
  } else {                  // hkT[1024][512]: A = WkT (M=1024), B = keys-split (N=512)
    m0 = (bid >> 3) * 64; n0 = (bid & 7) * 64; ldc = 512;
    Ah_g = wkthi; Al_g = wktlo; Bh_g = khi; Bl_g = klo; C = hkT;
  }

  __shared__ __align__(16) ushort Ah[64 * 40];   // row stride 40 (80B, 16B-aligned)
  __shared__ __align__(16) ushort Al[64 * 40];
  __shared__ __align__(16) ushort Bh[64 * 40];
  __shared__ __align__(16) ushort Bl[64 * 40];

  const int tid = threadIdx.x;
  const int srow = tid >> 2, skc = (tid & 3) * 8;         // staging: 64 rows x 32 k
  const size_t gA = (size_t)(m0 + srow) * 1024 + skc;
  const size_t gB = (size_t)(n0 + srow) * 1024 + skc;
  const int soff = srow * 40 + skc;

  uint4 rah = *(const uint4*)(Ah_g + gA);
  uint4 ral = *(const uint4*)(Al_g + gA);
  uint4 rbh = *(const uint4*)(Bh_g + gB);
  uint4 rbl = *(const uint4*)(Bl_g + gB);

  const int w = __builtin_amdgcn_readfirstlane(tid >> 6);
  const int lane = tid & 63;
  const int wm = (w >> 1) * 32, wn = (w & 1) * 32;
  const int fr = lane & 15, kg = lane >> 4;
  const int aoff = (wm + fr) * 40 + kg * 8;
  const int boff = (wn + fr) * 40 + kg * 8;

  f32x4_t acc[2][2] = {};

  for (int kk = 0; kk < 1024; kk += 32) {
    __syncthreads();
    *(uint4*)(Ah + soff) = rah;
    *(uint4*)(Al + soff) = ral;
    *(uint4*)(Bh + soff) = rbh;
    *(uint4*)(Bl + soff) = rbl;
    __syncthreads();

    if (kk + 32 < 1024) {
      rah = *(const uint4*)(Ah_g + gA + kk + 32);
      ral = *(const uint4*)(Al_g + gA + kk + 32);
      rbh = *(const uint4*)(Bh_g + gB + kk + 32);
      rbl = *(const uint4*)(Bl_g + gB + kk + 32);
    }

    bf16x8_t ah0 = *(const bf16x8_t*)(Ah + aoff);
    bf16x8_t ah1 = *(const bf16x8_t*)(Ah + aoff + 16 * 40);
    bf16x8_t al0 = *(const bf16x8_t*)(Al + aoff);
    bf16x8_t al1 = *(const bf16x8_t*)(Al + aoff + 16 * 40);
    bf16x8_t bh0 = *(const bf16x8_t*)(Bh + boff);
    bf16x8_t bh1 = *(const bf16x8_t*)(Bh + boff + 16 * 40);
    bf16x8_t bl0 = *(const bf16x8_t*)(Bl + boff);
    bf16x8_t bl1 = *(const bf16x8_t*)(Bl + boff + 16 * 40);

    // hi*hi
    acc[0][0] = __builtin_amdgcn_mfma_f32_16x16x32_bf16(ah0, bh0, acc[0][0], 0, 0, 0);
    acc[0][1] = __builtin_amdgcn_mfma_f32_16x16x32_bf16(ah0, bh1, acc[0][1], 0, 0, 0);
    acc[1][0] = __builtin_amdgcn_mfma_f32_16x16x32_bf16(ah1, bh0, acc[1][0], 0, 0, 0);
    acc[1][1] = __builtin_amdgcn_mfma_f32_16x16x32_bf16(ah1, bh1, acc[1][1], 0, 0, 0);
    // hi*lo
    acc[0][0] = __builtin_amdgcn_mfma_f32_16x16x32_bf16(ah0, bl0, acc[0][0], 0, 0, 0);
    acc[0][1] = __builtin_amdgcn_mfma_f32_16x16x32_bf16(ah0, bl1, acc[0][1], 0, 0, 0);
    acc[1][0] = __builtin_amdgcn_mfma_f32_16x16x32_bf16(ah1, bl0, acc[1][0], 0, 0, 0);
    acc[1][1] = __builtin_amdgcn_mfma_f32_16x16x32_bf16(ah1, bl1, acc[1][1], 0, 0, 0);
    // lo*hi
    acc[0][0] = __builtin_amdgcn_mfma_f32_16x16x32_bf16(al0, bh0, acc[0][0], 0, 0, 0);
    acc[0][1] = __builtin_amdgcn_mfma_f32_16x16x32_bf16(al0, bh1, acc[0][1], 0, 0, 0);
    acc[1][0] = __builtin_amdgcn_mfma_f32_16x16x32_bf16(al1, bh0, acc[1][0], 0, 0, 0);
    acc[1][1] = __builtin_amdgcn_mfma_f32_16x16x32_bf16(al1, bh1, acc[1][1], 0, 0, 0);
  }

#pragma unroll
  for (int fm = 0; fm < 2; ++fm)
#pragma unroll
    for (int fn = 0; fn < 2; ++fn) {
      const int col = n0 + wn + fn * 16 + fr;
#pragma unroll
      for (int j = 0; j < 4; ++j) {
        const int row = m0 + wm + fm * 16 + kg * 4 + j;
        C[(size_t)row * ldc + col] = acc[fm][fn][j];
      }
    }
}

// ---------------- Phase 2: logits, LDS-free ----------------
// 512 blocks x 4 waves. Wave: (b,h) = bid>>5, qb = (bid&31)*4 + wave, q0 = 2*qb.
// Lane l covers k = 4l..4l+3 (all 256 k). Loop d in groups of 4.
#define COMP(vk, hq0v, hq1v, vad)                                     \
  {                                                                   \
    float e0 = __builtin_amdgcn_exp2f(hq0v + vk.x);                   \
    float e1 = __builtin_amdgcn_exp2f(hq0v + vk.y);                   \
    float e2 = __builtin_amdgcn_exp2f(hq0v + vk.z);                   \
    float e3 = __builtin_amdgcn_exp2f(hq0v + vk.w);                   \
    acc00 += vad * __builtin_amdgcn_rcpf(e0 + 1.0f);                  \
    acc01 += vad * __builtin_amdgcn_rcpf(e1 + 1.0f);                  \
    acc02 += vad * __builtin_amdgcn_rcpf(e2 + 1.0f);                  \
    acc03 += vad * __builtin_amdgcn_rcpf(e3 + 1.0f);                  \
    float f0 = __builtin_amdgcn_exp2f(hq1v + vk.x);                   \
    float f1 = __builtin_amdgcn_exp2f(hq1v + vk.y);                   \
    float f2 = __builtin_amdgcn_exp2f(hq1v + vk.z);                   \
    float f3 = __builtin_amdgcn_exp2f(hq1v + vk.w);                   \
    acc10 += vad * __builtin_amdgcn_rcpf(f0 + 1.0f);                  \
    acc11 += vad * __builtin_amdgcn_rcpf(f1 + 1.0f);                  \
    acc12 += vad * __builtin_amdgcn_rcpf(f2 + 1.0f);                  \
    acc13 += vad * __builtin_amdgcn_rcpf(f3 + 1.0f);                  \
  }

__global__ __launch_bounds__(256) void logits_v3(
    const float* __restrict__ hq_f, const float* __restrict__ hkT,
    const float* __restrict__ Va, const int* __restrict__ mask,
    float* __restrict__ logits)
{
  const int tid = threadIdx.x;
  const int lane = tid & 63;
  const int w = __builtin_amdgcn_readfirstlane(tid >> 6);
  const int bid = blockIdx.x;
  const int hb = bid >> 5;           // 0..15
  const int b = hb & 1, h = hb >> 1;
  const int qb = (bid & 31) * 4 + w; // 0..127
  const int q0 = qb * 2;

  int4 mk = *(const int4*)(mask + b * 256 + 4 * lane);
  const float pen0 = 99.0f * (1.0f - (float)mk.x);
  const float pen1 = 99.0f * (1.0f - (float)mk.y);
  const float pen2 = 99.0f * (1.0f - (float)mk.z);
  const float pen3 = 99.0f * (1.0f - (float)mk.w);

  float ssum = Va[h * 128 + lane] + Va[h * 128 + 64 + lane];
#pragma unroll
  for (int off = 32; off; off >>= 1) ssum += __shfl_xor(ssum, off, 64);

  const float* hkbase = hkT + (size_t)(h * 128) * 512 + b * 256 + 4 * lane;
  const float* hqr0 = hq_f + (size_t)(b * 256 + q0) * 1024 + h * 128;  // wave-uniform
  const float* hqr1 = hqr0 + 1024;
  const float* vap = Va + h * 128;

  float acc00 = 0.f, acc01 = 0.f, acc02 = 0.f, acc03 = 0.f;
  float acc10 = 0.f, acc11 = 0.f, acc12 = 0.f, acc13 = 0.f;

  float4 vk0 = *(const float4*)(hkbase + 0 * 512);
  float4 vk1 = *(const float4*)(hkbase + 1 * 512);
  float4 vk2 = *(const float4*)(hkbase + 2 * 512);
  float4 vk3 = *(const float4*)(hkbase + 3 * 512);
  float4 hqA = *(const float4*)(hqr0);
  float4 hqB = *(const float4*)(hqr1);
  float4 va4 = *(const float4*)(vap);

  for (int g = 0; g < 32; ++g) {
    float4 nvk0, nvk1, nvk2, nvk3, nhqA, nhqB, nva4;
    if (g < 31) {
      const float* hb2 = hkbase + (size_t)(4 * g + 4) * 512;
      nvk0 = *(const float4*)(hb2 + 0 * 512);
      nvk1 = *(const float4*)(hb2 + 1 * 512);
      nvk2 = *(const float4*)(hb2 + 2 * 512);
      nvk3 = *(const float4*)(hb2 + 3 * 512);
      nhqA = *(const float4*)(hqr0 + 4 * g + 4);
      nhqB = *(const float4*)(hqr1 + 4 * g + 4);
      nva4 = *(const float4*)(vap + 4 * g + 4);
    }
    COMP(vk0, hqA.x, hqB.x, va4.x);
    COMP(vk1, hqA.y, hqB.y, va4.y);
    COMP(vk2, hqA.z, hqB.z, va4.z);
    COMP(vk3, hqA.w, hqB.w, va4.w);
    if (g < 31) {
      vk0 = nvk0; vk1 = nvk1; vk2 = nvk2; vk3 = nvk3;
      hqA = nhqA; hqB = nhqB; va4 = nva4;
    }
  }

  float* lp = logits + ((size_t)((b * 8 + h) * 256) + q0) * 256 + 4 * lane;
  float4 o0, o1;
  o0.x = ssum - 2.0f * acc00 - pen0;
  o0.y = ssum - 2.0f * acc01 - pen1;
  o0.z = ssum - 2.0f * acc02 - pen2;
  o0.w = ssum - 2.0f * acc03 - pen3;
  o1.x = ssum - 2.0f * acc10 - pen0;
  o1.y = ssum - 2.0f * acc11 - pen1;
  o1.z = ssum - 2.0f * acc12 - pen2;
  o1.w = ssum - 2.0f * acc13 - pen3;
  *(float4*)(lp) = o0;
  *(float4*)(lp + 256) = o1;
}

// ---------------- Phase 3: softmax (in place) + PV ----------------
__global__ __launch_bounds__(256) void softmax_pv(
    const float* __restrict__ values,
    float* __restrict__ weights,
    float* __restrict__ ctx)
{
  __shared__ __align__(16) float w_lds[8 * 256];
  const int tid = threadIdx.x;
  const int b = blockIdx.z, h = blockIdx.y, q0 = blockIdx.x * 8;
  const int wave = tid >> 6, lane = tid & 63;

#pragma unroll
  for (int r = 0; r < 2; ++r) {
    const int row = wave * 2 + r;
    float* lp = &weights[((size_t)(b * 8 + h) * 256 + q0 + row) * 256];
    float4 L = *(const float4*)&lp[lane * 4];
    float m = fmaxf(fmaxf(L.x, L.y), fmaxf(L.z, L.w));
#pragma unroll
    for (int off = 32; off; off >>= 1) m = fmaxf(m, __shfl_xor(m, off, 64));
    float4 P;
    P.x = __builtin_amdgcn_exp2f((L.x - m) * LOG2E);
    P.y = __builtin_amdgcn_exp2f((L.y - m) * LOG2E);
    P.z = __builtin_amdgcn_exp2f((L.z - m) * LOG2E);
    P.w = __builtin_amdgcn_exp2f((L.w - m) * LOG2E);
    float s = (P.x + P.y) + (P.z + P.w);
#pragma unroll
    for (int off = 32; off; off >>= 1) s += __shfl_xor(s, off, 64);
    float inv = 1.0f / s;
    P.x *= inv; P.y *= inv; P.z *= inv; P.w *= inv;
    *(float4*)&w_lds[row * 256 + lane * 4] = P;
    *(float4*)&lp[lane * 4] = P;
  }
  __syncthreads();

  const int q = tid >> 5, dq = tid & 31;
  const float* vb = values + (size_t)(b * 256) * 1024 + h * 128 + dq * 4;
  const float* wrow = w_lds + q * 256;
  float4 accE = make_float4(0, 0, 0, 0), accO = make_float4(0, 0, 0, 0);
#pragma unroll 4
  for (int k = 0; k < 256; k += 2) {
    float4 v0 = *(const float4*)&vb[k * 1024];
    float4 v1 = *(const float4*)&vb[(k + 1) * 1024];
    float w0 = wrow[k], w1 = wrow[k + 1];
    accE.x += w0 * v0.x; accE.y += w0 * v0.y; accE.z += w0 * v0.z; accE.w += w0 * v0.w;
    accO.x += w1 * v1.x; accO.y += w1 * v1.y; accO.z += w1 * v1.z; accO.w += w1 * v1.w;
  }
  float4 o;
  o.x = accE.x + accO.x; o.y = accE.y + accO.y; o.z = accE.z + accO.z; o.w = accE.w + accO.w;
  *(float4*)&ctx[(size_t)(b * 256 + q0 + q) * 1024 + h * 128 + dq * 4] = o;
}

extern "C" void kernel_launch(void* const* d_in, const int* in_sizes, int n_in,
                              void* d_out, int out_size, void* d_ws, size_t ws_size,
                              hipStream_t stream) {
  const float* query  = (const float*)d_in[0];
  const float* keys   = (const float*)d_in[1];
  const float* values = (const float*)d_in[2];
  const int*   mask   = (const int*)d_in[3];
  const float* Wq     = (const float*)d_in[4];
  const float* Wk     = (const float*)d_in[5];
  const float* Va     = (const float*)d_in[6];

  float* ctx     = (float*)d_out;            // [2,256,1024]
  float* weights = ctx + 524288;             // [2,8,256,256]

  // ws layout (16 MB total):
  ushort* qhi   = (ushort*)d_ws;             // 512K elems each
  ushort* qlo   = qhi + 524288;
  ushort* khi   = qlo + 524288;
  ushort* klo   = khi + 524288;
  ushort* wqthi = klo + 524288;              // 1M elems each
  ushort* wqtlo = wqthi + 1048576;
  ushort* wkthi = wqtlo + 1048576;
  ushort* wktlo = wkthi + 1048576;
  float*  hq_f  = (float*)(wktlo + 1048576); // [512][1024]
  float*  hkT   = hq_f + 524288;             // [1024][512]

  split_A <<<dim3(512, 2), 256, 0, stream>>>(query, keys, qhi, qlo, khi, klo);
  split_WT<<<dim3(16, 16, 2), 256, 0, stream>>>(Wq, Wk, wqthi, wqtlo, wkthi, wktlo);
  gemm_mfma<<<dim3(128, 2), 256, 0, stream>>>(qhi, qlo, khi, klo,
                                              wqthi, wqtlo, wkthi, wktlo, hq_f, hkT);
  logits_v3<<<dim3(512), 256, 0, stream>>>(hq_f, hkT, Va, mask, weights);
  softmax_pv<<<dim3(32, 8, 2), 256, 0, stream>>>(values, weights, ctx);
}

// Round 6
// 73.105 us; speedup vs baseline: 2.4273x; 1.0610x over previous
//
#include <hip/hip_runtime.h>
#include <hip/hip_bf16.h>

// MultiHeadAttention (additive/Bahdanau): B=2, Q=K=256, HIDDEN=1024, 8 heads x 128
// Pipeline (3 kernels):
//  1) prep:      split query/keys -> bf16 hi/lo; W^T*2log2e -> bf16 hi/lo (LDS transpose)
//  2) gemm_mfma: 3-term bf16 MFMA GEMMs -> hq_f[512][1024], hkT[1024][512] (transposed free)
//  3) attn_fused: logits (LDS-free, lane-local d-reduce) -> softmax in regs -> weights out
//                 -> PV -> ctx out
// tanh(x) = 1 - 2/(e^{2x}+1); a = 2log2e*x -> e^{2x} = 2^a. Saturates correctly at +-inf.
// Requires ws_size >= 16 MB (verified in earlier rounds).

#define TANH_SCALE 2.88539008177792681472f   // 2*log2(e)
#define LOG2E      1.44269504088896340736f

typedef __attribute__((ext_vector_type(8))) short bf16x8_t;   // 8 bf16 = 4 VGPRs
typedef __attribute__((ext_vector_type(4))) float f32x4_t;

__device__ inline ushort bf16_rne(float f) {
  unsigned u = __float_as_uint(f);
  u += 0x7FFFu + ((u >> 16) & 1u);
  return (ushort)(u >> 16);
}
__device__ inline float bf16_to_f(ushort h) { return __uint_as_float((unsigned)h << 16); }
__device__ inline void split1(float v, ushort& hi, ushort& lo) {
  hi = bf16_rne(v);
  lo = bf16_rne(v - bf16_to_f(hi));
}

// ---------------- Kernel 1: prep (split_A + split_WT fused) ----------------
// bid < 1024: elementwise split of query/keys (z = bid>>9, blk = bid&511)
// bid >= 1024: W^T transpose+scale+split (idx = bid-1024: z = idx>>8, x = idx&15, y = (idx>>4)&15)
__global__ __launch_bounds__(256) void prep(
    const float* __restrict__ query, const float* __restrict__ keys,
    const float* __restrict__ Wq, const float* __restrict__ Wk,
    ushort* __restrict__ qhi, ushort* __restrict__ qlo,
    ushort* __restrict__ khi, ushort* __restrict__ klo,
    ushort* __restrict__ wqthi, ushort* __restrict__ wqtlo,
    ushort* __restrict__ wkthi, ushort* __restrict__ wktlo)
{
  __shared__ float t[64][65];
  const int bid = blockIdx.x, tid = threadIdx.x;
  if (bid < 1024) {
    const int z = bid >> 9;
    const float* in = z ? keys : query;
    ushort* hi = z ? khi : qhi;
    ushort* lo = z ? klo : qlo;
    const size_t i = ((size_t)(bid & 511) * 256 + tid) * 4;
    float4 v = *(const float4*)(in + i);
    ushort h0, h1, h2, h3, l0, l1, l2, l3;
    split1(v.x, h0, l0); split1(v.y, h1, l1);
    split1(v.z, h2, l2); split1(v.w, h3, l3);
    *(ushort4*)(hi + i) = make_ushort4(h0, h1, h2, h3);
    *(ushort4*)(lo + i) = make_ushort4(l0, l1, l2, l3);
  } else {
    const int idx = bid - 1024;
    const int z = idx >> 8;
    const float* W = z ? Wk : Wq;
    ushort* thi = z ? wkthi : wqthi;
    ushort* tlo = z ? wktlo : wqtlo;
    const int n0 = (idx & 15) * 64, h0 = ((idx >> 4) & 15) * 64;
    const int r = tid >> 4, c = (tid & 15) * 4;
#pragma unroll
    for (int i = 0; i < 4; ++i) {
      const int rr = r + i * 16;
      float4 wv = *(const float4*)(W + (size_t)(h0 + rr) * 1024 + n0 + c);
      t[rr][c + 0] = wv.x; t[rr][c + 1] = wv.y;
      t[rr][c + 2] = wv.z; t[rr][c + 3] = wv.w;
    }
    __syncthreads();
#pragma unroll
    for (int i = 0; i < 4; ++i) {
      const int rr = r + i * 16;   // local n row of output
      ushort h0v, h1v, h2v, h3v, l0v, l1v, l2v, l3v;
      split1(t[c + 0][rr] * TANH_SCALE, h0v, l0v);
      split1(t[c + 1][rr] * TANH_SCALE, h1v, l1v);
      split1(t[c + 2][rr] * TANH_SCALE, h2v, l2v);
      split1(t[c + 3][rr] * TANH_SCALE, h3v, l3v);
      *(ushort4*)(thi + (size_t)(n0 + rr) * 1024 + h0 + c) = make_ushort4(h0v, h1v, h2v, h3v);
      *(ushort4*)(tlo + (size_t)(n0 + rr) * 1024 + h0 + c) = make_ushort4(l0v, l1v, l2v, l3v);
    }
  }
}

// ---------------- Kernel 2: MFMA GEMM, 3-term bf16 split ----------------
// grid (128, 2). Block: 64x64 C-tile, 4 waves of 32x32, K-step 32, K=1024.
// A-frag: row = lane&15 (+16*fm), k = (lane>>4)*8 + e.  B-frag symmetric.
// C/D: col = lane&15, row = (lane>>4)*4 + j.
__global__ __launch_bounds__(256) void gemm_mfma(
    const ushort* __restrict__ qhi, const ushort* __restrict__ qlo,
    const ushort* __restrict__ khi, const ushort* __restrict__ klo,
    const ushort* __restrict__ wqthi, const ushort* __restrict__ wqtlo,
    const ushort* __restrict__ wkthi, const ushort* __restrict__ wktlo,
    float* __restrict__ hq_f, float* __restrict__ hkT)
{
  const int z = blockIdx.y;
  const int bid = blockIdx.x;
  int m0, n0, ldc;
  const ushort *Ah_g, *Al_g, *Bh_g, *Bl_g;
  float* C;
  if (z == 0) {             // hq_f[512][1024]: A = query-split (M=512), B = WqT (N=1024)
    m0 = (bid >> 4) * 64; n0 = (bid & 15) * 64; ldc = 1024;
    Ah_g = qhi; Al_g = qlo; Bh_g = wqthi; Bl_g = wqtlo; C = hq_f;
  } else {                  // hkT[1024][512]: A = WkT (M=1024), B = keys-split (N=512)
    m0 = (bid >> 3) * 64; n0 = (bid & 7) * 64; ldc = 512;
    Ah_g = wkthi; Al_g = wktlo; Bh_g = khi; Bl_g = klo; C = hkT;
  }

  __shared__ __align__(16) ushort Ah[64 * 40];   // row stride 40 (80B, 16B-aligned)
  __shared__ __align__(16) ushort Al[64 * 40];
  __shared__ __align__(16) ushort Bh[64 * 40];
  __shared__ __align__(16) ushort Bl[64 * 40];

  const int tid = threadIdx.x;
  const int srow = tid >> 2, skc = (tid & 3) * 8;         // staging: 64 rows x 32 k
  const size_t gA = (size_t)(m0 + srow) * 1024 + skc;
  const size_t gB = (size_t)(n0 + srow) * 1024 + skc;
  const int soff = srow * 40 + skc;

  uint4 rah = *(const uint4*)(Ah_g + gA);
  uint4 ral = *(const uint4*)(Al_g + gA);
  uint4 rbh = *(const uint4*)(Bh_g + gB);
  uint4 rbl = *(const uint4*)(Bl_g + gB);

  const int w = __builtin_amdgcn_readfirstlane(tid >> 6);
  const int lane = tid & 63;
  const int wm = (w >> 1) * 32, wn = (w & 1) * 32;
  const int fr = lane & 15, kg = lane >> 4;
  const int aoff = (wm + fr) * 40 + kg * 8;
  const int boff = (wn + fr) * 40 + kg * 8;

  f32x4_t acc[2][2] = {};

  for (int kk = 0; kk < 1024; kk += 32) {
    __syncthreads();
    *(uint4*)(Ah + soff) = rah;
    *(uint4*)(Al + soff) = ral;
    *(uint4*)(Bh + soff) = rbh;
    *(uint4*)(Bl + soff) = rbl;
    __syncthreads();

    if (kk + 32 < 1024) {
      rah = *(const uint4*)(Ah_g + gA + kk + 32);
      ral = *(const uint4*)(Al_g + gA + kk + 32);
      rbh = *(const uint4*)(Bh_g + gB + kk + 32);
      rbl = *(const uint4*)(Bl_g + gB + kk + 32);
    }

    bf16x8_t ah0 = *(const bf16x8_t*)(Ah + aoff);
    bf16x8_t ah1 = *(const bf16x8_t*)(Ah + aoff + 16 * 40);
    bf16x8_t al0 = *(const bf16x8_t*)(Al + aoff);
    bf16x8_t al1 = *(const bf16x8_t*)(Al + aoff + 16 * 40);
    bf16x8_t bh0 = *(const bf16x8_t*)(Bh + boff);
    bf16x8_t bh1 = *(const bf16x8_t*)(Bh + boff + 16 * 40);
    bf16x8_t bl0 = *(const bf16x8_t*)(Bl + boff);
    bf16x8_t bl1 = *(const bf16x8_t*)(Bl + boff + 16 * 40);

    acc[0][0] = __builtin_amdgcn_mfma_f32_16x16x32_bf16(ah0, bh0, acc[0][0], 0, 0, 0);
    acc[0][1] = __builtin_amdgcn_mfma_f32_16x16x32_bf16(ah0, bh1, acc[0][1], 0, 0, 0);
    acc[1][0] = __builtin_amdgcn_mfma_f32_16x16x32_bf16(ah1, bh0, acc[1][0], 0, 0, 0);
    acc[1][1] = __builtin_amdgcn_mfma_f32_16x16x32_bf16(ah1, bh1, acc[1][1], 0, 0, 0);
    acc[0][0] = __builtin_amdgcn_mfma_f32_16x16x32_bf16(ah0, bl0, acc[0][0], 0, 0, 0);
    acc[0][1] = __builtin_amdgcn_mfma_f32_16x16x32_bf16(ah0, bl1, acc[0][1], 0, 0, 0);
    acc[1][0] = __builtin_amdgcn_mfma_f32_16x16x32_bf16(ah1, bl0, acc[1][0], 0, 0, 0);
    acc[1][1] = __builtin_amdgcn_mfma_f32_16x16x32_bf16(ah1, bl1, acc[1][1], 0, 0, 0);
    acc[0][0] = __builtin_amdgcn_mfma_f32_16x16x32_bf16(al0, bh0, acc[0][0], 0, 0, 0);
    acc[0][1] = __builtin_amdgcn_mfma_f32_16x16x32_bf16(al0, bh1, acc[0][1], 0, 0, 0);
    acc[1][0] = __builtin_amdgcn_mfma_f32_16x16x32_bf16(al1, bh0, acc[1][0], 0, 0, 0);
    acc[1][1] = __builtin_amdgcn_mfma_f32_16x16x32_bf16(al1, bh1, acc[1][1], 0, 0, 0);
  }

#pragma unroll
  for (int fm = 0; fm < 2; ++fm)
#pragma unroll
    for (int fn = 0; fn < 2; ++fn) {
      const int col = n0 + wn + fn * 16 + fr;
#pragma unroll
      for (int j = 0; j < 4; ++j) {
        const int row = m0 + wm + fm * 16 + kg * 4 + j;
        C[(size_t)row * ldc + col] = acc[fm][fn][j];
      }
    }
}

// ---------------- Kernel 3: fused logits + softmax + PV ----------------
// 512 blocks x 256 thr. Block: (b,h) = bid>>5, q-tile = (bid&31)*8.
// Wave w owns q rows {2w, 2w+1}; lane l covers k = 4l..4l+3 (all 256 k).
// Then softmax on registers (wave-wide shuffles), weights -> global + LDS, PV -> ctx.
#define COMP(vk, hq0v, hq1v, vad)                                     \
  {                                                                   \
    float e0 = __builtin_amdgcn_exp2f(hq0v + vk.x);                   \
    float e1 = __builtin_amdgcn_exp2f(hq0v + vk.y);                   \
    float e2 = __builtin_amdgcn_exp2f(hq0v + vk.z);                   \
    float e3 = __builtin_amdgcn_exp2f(hq0v + vk.w);                   \
    acc00 += vad * __builtin_amdgcn_rcpf(e0 + 1.0f);                  \
    acc01 += vad * __builtin_amdgcn_rcpf(e1 + 1.0f);                  \
    acc02 += vad * __builtin_amdgcn_rcpf(e2 + 1.0f);                  \
    acc03 += vad * __builtin_amdgcn_rcpf(e3 + 1.0f);                  \
    float f0 = __builtin_amdgcn_exp2f(hq1v + vk.x);                   \
    float f1 = __builtin_amdgcn_exp2f(hq1v + vk.y);                   \
    float f2 = __builtin_amdgcn_exp2f(hq1v + vk.z);                   \
    float f3 = __builtin_amdgcn_exp2f(hq1v + vk.w);                   \
    acc10 += vad * __builtin_amdgcn_rcpf(f0 + 1.0f);                  \
    acc11 += vad * __builtin_amdgcn_rcpf(f1 + 1.0f);                  \
    acc12 += vad * __builtin_amdgcn_rcpf(f2 + 1.0f);                  \
    acc13 += vad * __builtin_amdgcn_rcpf(f3 + 1.0f);                  \
  }

__global__ __launch_bounds__(256) void attn_fused(
    const float* __restrict__ hq_f, const float* __restrict__ hkT,
    const float* __restrict__ Va, const int* __restrict__ mask,
    const float* __restrict__ values,
    float* __restrict__ weights, float* __restrict__ ctx)
{
  __shared__ __align__(16) float w_lds[8 * 256];
  const int tid = threadIdx.x;
  const int lane = tid & 63;
  const int w = __builtin_amdgcn_readfirstlane(tid >> 6);
  const int bid = blockIdx.x;
  const int hb = bid >> 5;           // 0..15
  const int b = hb & 1, h = hb >> 1;
  const int qt = (bid & 31) * 8;     // q-tile base
  const int q0 = qt + w * 2;         // this wave's first q row

  int4 mk = *(const int4*)(mask + b * 256 + 4 * lane);
  const float pen0 = 99.0f * (1.0f - (float)mk.x);
  const float pen1 = 99.0f * (1.0f - (float)mk.y);
  const float pen2 = 99.0f * (1.0f - (float)mk.z);
  const float pen3 = 99.0f * (1.0f - (float)mk.w);

  float ssum = Va[h * 128 + lane] + Va[h * 128 + 64 + lane];
#pragma unroll
  for (int off = 32; off; off >>= 1) ssum += __shfl_xor(ssum, off, 64);

  const float* hkbase = hkT + (size_t)(h * 128) * 512 + b * 256 + 4 * lane;
  const float* hqr0 = hq_f + (size_t)(b * 256 + q0) * 1024 + h * 128;  // wave-uniform
  const float* hqr1 = hqr0 + 1024;
  const float* vap = Va + h * 128;

  float acc00 = 0.f, acc01 = 0.f, acc02 = 0.f, acc03 = 0.f;
  float acc10 = 0.f, acc11 = 0.f, acc12 = 0.f, acc13 = 0.f;

  float4 vk0 = *(const float4*)(hkbase + 0 * 512);
  float4 vk1 = *(const float4*)(hkbase + 1 * 512);
  float4 vk2 = *(const float4*)(hkbase + 2 * 512);
  float4 vk3 = *(const float4*)(hkbase + 3 * 512);
  float4 hqA = *(const float4*)(hqr0);
  float4 hqB = *(const float4*)(hqr1);
  float4 va4 = *(const float4*)(vap);

  for (int g = 0; g < 32; ++g) {
    float4 nvk0, nvk1, nvk2, nvk3, nhqA, nhqB, nva4;
    if (g < 31) {  // prefetch next d-group (uniform branch)
      const float* hb2 = hkbase + (size_t)(4 * g + 4) * 512;
      nvk0 = *(const float4*)(hb2 + 0 * 512);
      nvk1 = *(const float4*)(hb2 + 1 * 512);
      nvk2 = *(const float4*)(hb2 + 2 * 512);
      nvk3 = *(const float4*)(hb2 + 3 * 512);
      nhqA = *(const float4*)(hqr0 + 4 * g + 4);
      nhqB = *(const float4*)(hqr1 + 4 * g + 4);
      nva4 = *(const float4*)(vap + 4 * g + 4);
    }
    COMP(vk0, hqA.x, hqB.x, va4.x);
    COMP(vk1, hqA.y, hqB.y, va4.y);
    COMP(vk2, hqA.z, hqB.z, va4.z);
    COMP(vk3, hqA.w, hqB.w, va4.w);
    if (g < 31) {
      vk0 = nvk0; vk1 = nvk1; vk2 = nvk2; vk3 = nvk3;
      hqA = nhqA; hqB = nhqB; va4 = nva4;
    }
  }

  // logits (natural scale), penalty baked
  float4 L0, L1;
  L0.x = ssum - 2.0f * acc00 - pen0;
  L0.y = ssum - 2.0f * acc01 - pen1;
  L0.z = ssum - 2.0f * acc02 - pen2;
  L0.w = ssum - 2.0f * acc03 - pen3;
  L1.x = ssum - 2.0f * acc10 - pen0;
  L1.y = ssum - 2.0f * acc11 - pen1;
  L1.z = ssum - 2.0f * acc12 - pen2;
  L1.w = ssum - 2.0f * acc13 - pen3;

  // softmax per q row (row spread across the wave: 64 lanes x 4 k)
  float m0 = fmaxf(fmaxf(L0.x, L0.y), fmaxf(L0.z, L0.w));
  float m1 = fmaxf(fmaxf(L1.x, L1.y), fmaxf(L1.z, L1.w));
#pragma unroll
  for (int off = 32; off; off >>= 1) {
    m0 = fmaxf(m0, __shfl_xor(m0, off, 64));
    m1 = fmaxf(m1, __shfl_xor(m1, off, 64));
  }
  float4 P0, P1;
  P0.x = __builtin_amdgcn_exp2f((L0.x - m0) * LOG2E);
  P0.y = __builtin_amdgcn_exp2f((L0.y - m0) * LOG2E);
  P0.z = __builtin_amdgcn_exp2f((L0.z - m0) * LOG2E);
  P0.w = __builtin_amdgcn_exp2f((L0.w - m0) * LOG2E);
  P1.x = __builtin_amdgcn_exp2f((L1.x - m1) * LOG2E);
  P1.y = __builtin_amdgcn_exp2f((L1.y - m1) * LOG2E);
  P1.z = __builtin_amdgcn_exp2f((L1.z - m1) * LOG2E);
  P1.w = __builtin_amdgcn_exp2f((L1.w - m1) * LOG2E);
  float s0 = (P0.x + P0.y) + (P0.z + P0.w);
  float s1 = (P1.x + P1.y) + (P1.z + P1.w);
#pragma unroll
  for (int off = 32; off; off >>= 1) {
    s0 += __shfl_xor(s0, off, 64);
    s1 += __shfl_xor(s1, off, 64);
  }
  float inv0 = 1.0f / s0, inv1 = 1.0f / s1;
  P0.x *= inv0; P0.y *= inv0; P0.z *= inv0; P0.w *= inv0;
  P1.x *= inv1; P1.y *= inv1; P1.z *= inv1; P1.w *= inv1;

  float* wp = weights + ((size_t)((b * 8 + h) * 256) + q0) * 256 + 4 * lane;
  *(float4*)(wp) = P0;
  *(float4*)(wp + 256) = P1;
  *(float4*)&w_lds[(w * 2 + 0) * 256 + 4 * lane] = P0;
  *(float4*)&w_lds[(w * 2 + 1) * 256 + 4 * lane] = P1;
  __syncthreads();

  // PV: thread -> (q = tid>>5 in tile, d4 = (tid&31)*4); loop k, coalesced float4 V loads
  const int q = tid >> 5, dq = tid & 31;
  const float* vb = values + (size_t)(b * 256) * 1024 + h * 128 + dq * 4;
  const float* wrow = w_lds + q * 256;
  float4 accE = make_float4(0, 0, 0, 0), accO = make_float4(0, 0, 0, 0);
#pragma unroll 4
  for (int k = 0; k < 256; k += 2) {
    float4 v0 = *(const float4*)&vb[k * 1024];
    float4 v1 = *(const float4*)&vb[(k + 1) * 1024];
    float w0 = wrow[k], w1 = wrow[k + 1];
    accE.x += w0 * v0.x; accE.y += w0 * v0.y; accE.z += w0 * v0.z; accE.w += w0 * v0.w;
    accO.x += w1 * v1.x; accO.y += w1 * v1.y; accO.z += w1 * v1.z; accO.w += w1 * v1.w;
  }
  float4 o;
  o.x = accE.x + accO.x; o.y = accE.y + accO.y; o.z = accE.z + accO.z; o.w = accE.w + accO.w;
  *(float4*)&ctx[(size_t)(b * 256 + qt + q) * 1024 + h * 128 + dq * 4] = o;
}

extern "C" void kernel_launch(void* const* d_in, const int* in_sizes, int n_in,
                              void* d_out, int out_size, void* d_ws, size_t ws_size,
                              hipStream_t stream) {
  const float* query  = (const float*)d_in[0];
  const float* keys   = (const float*)d_in[1];
  const float* values = (const float*)d_in[2];
  const int*   mask   = (const int*)d_in[3];
  const float* Wq     = (const float*)d_in[4];
  const float* Wk     = (const float*)d_in[5];
  const float* Va     = (const float*)d_in[6];

  float* ctx     = (float*)d_out;            // [2,256,1024]
  float* weights = ctx + 524288;             // [2,8,256,256]

  // ws layout (16 MB total):
  ushort* qhi   = (ushort*)d_ws;             // 512K elems each
  ushort* qlo   = qhi + 524288;
  ushort* khi   = qlo + 524288;
  ushort* klo   = khi + 524288;
  ushort* wqthi = klo + 524288;              // 1M elems each
  ushort* wqtlo = wqthi + 1048576;
  ushort* wkthi = wqtlo + 1048576;
  ushort* wktlo = wkthi + 1048576;
  float*  hq_f  = (float*)(wktlo + 1048576); // [512][1024]
  float*  hkT   = hq_f + 524288;             // [1024][512]

  prep<<<dim3(1536), 256, 0, stream>>>(query, keys, Wq, Wk,
                                       qhi, qlo, khi, klo,
                                       wqthi, wqtlo, wkthi, wktlo);
  gemm_mfma<<<dim3(128, 2), 256, 0, stream>>>(qhi, qlo, khi, klo,
                                              wqthi, wqtlo, wkthi, wktlo, hq_f, hkT);
  attn_fused<<<dim3(512), 256, 0, stream>>>(hq_f, hkT, Va, mask, values, weights, ctx);
}